// Round 10
// baseline (27.668 us; speedup 1.0000x reference)
//
#include <hip/hip_runtime.h>

// CountHistogram: B=128, C=4, Q=32, D=2048, NBINS=30
// out[b,c,q,bin] = sum_d [ bin(simmat[b,c,q,d]) == bin ] * (dtoks[b,d]!=-1) * (qtoks[b,q]!=-1)
//
// Design (R9 = R4 + ONE diff: dtoks staged once per block as packed LDS
//   nibble-mask). Theory: per-wave dtoks re-reads added 134 MB of L2/L3-side
//   traffic (equal to the simmat stream) + 2x VMEM issue in the loop.
//   - stage: thread t loads dtoks[b][8t..8t+7] (2 int4), packs 8 validity
//     bits into one byte, stores as word smask[t] (no write conflicts).
//     One __syncthreads, then waves are independent.
//   - loop: lane reads smask[j*32 + (lane>>1)] (broadcast word, conflict-free),
//     nibble = bits 4*(lane&1)..+3 -> masks for its 4 elements.
//   - rest identical to R4: one wave per row; 8 sub-histograms per wave
//     (8-lane groups, stride 33 -> bank(bin,g)=(bin+g)%32, cross-group
//     conflict-free); masked elems -> dead slot 31 (unconditional ds_add);
//     NT simmat loads; bit-exact (x+1.00001f)*14.5f.

#define NBINS   30
#define DIM     2048
#define QDIM    32
#define CDIM    4
#define BDIM    128
#define GSTRIDE 33                                   // words per group histogram
#define WSTRIDE (8 * GSTRIDE)                        // 264 words per wave

typedef float nfloat4 __attribute__((ext_vector_type(4)));
typedef int   nint4   __attribute__((ext_vector_type(4)));

__global__ __launch_bounds__(256) void CountHistogram_kernel(
    const float* __restrict__ simmat,
    const int*   __restrict__ dtoks,
    const int*   __restrict__ qtoks,
    float*       __restrict__ out)
{
    const int tid  = threadIdx.x;
    const int wave = tid >> 6;
    const int lane = tid & 63;
    const int row  = blockIdx.x * 4 + wave;          // = b*C*Q + c*Q + q
    const int q    = row & (QDIM - 1);
    const int b    = blockIdx.x >> 5;                // all 4 rows of a block share b

    __shared__ int hs[4 * WSTRIDE];                  // 4 waves * 8 groups * 33 words
    __shared__ int smask[256];                       // byte-per-8-elems validity mask

    // ---- stage dtoks[b] -> packed mask, once per block ----
    {
        const nint4* dt = (const nint4*)(dtoks + (size_t)b * DIM);
        const nint4 t0 = dt[2 * tid];
        const nint4 t1 = dt[2 * tid + 1];
        unsigned int m = (unsigned int)(t0.x != -1)
                       | ((unsigned int)(t0.y != -1) << 1)
                       | ((unsigned int)(t0.z != -1) << 2)
                       | ((unsigned int)(t0.w != -1) << 3)
                       | ((unsigned int)(t1.x != -1) << 4)
                       | ((unsigned int)(t1.y != -1) << 5)
                       | ((unsigned int)(t1.z != -1) << 6)
                       | ((unsigned int)(t1.w != -1) << 7);
        smask[tid] = (int)m;
    }

    // zero histograms (same-wave DS ordering protects later atomics)
    int* hw = hs + wave * WSTRIDE;
    hw[lane] = 0; hw[lane + 64] = 0; hw[lane + 128] = 0; hw[lane + 192] = 0;
    if (lane < WSTRIDE - 256) hw[lane + 256] = 0;

    __syncthreads();

    const int qt = qtoks[b * QDIM + q];              // wave-uniform
    int* hg = hw + (lane >> 3) * GSTRIDE;            // this lane's group histogram
    const int nibsh = 4 * (lane & 1);                // nibble position in mask word

    if (qt != -1) {
        const nfloat4* sm = (const nfloat4*)(simmat + (size_t)row * DIM);
        #pragma unroll
        for (int j = 0; j < 8; ++j) {
            const nfloat4 s = __builtin_nontemporal_load(&sm[j * 64 + lane]);
            const unsigned int nib =
                ((unsigned int)smask[j * 32 + (lane >> 1)] >> nibsh) & 0xFu;
            // bit-exact: ((x+1.00001f)/2.0f)*29.0f == (x+1.00001f)*14.5f
            int b0 = (int)((s.x + 1.00001f) * 14.5f);
            int b1 = (int)((s.y + 1.00001f) * 14.5f);
            int b2 = (int)((s.z + 1.00001f) * 14.5f);
            int b3 = (int)((s.w + 1.00001f) * 14.5f);
            // masked elements -> dead slot 31 (bins 30..32 never read back)
            b0 = (nib & 1u) ? b0 : 31;
            b1 = (nib & 2u) ? b1 : 31;
            b2 = (nib & 4u) ? b2 : 31;
            b3 = (nib & 8u) ? b3 : 31;
            atomicAdd(&hg[b0], 1);
            atomicAdd(&hg[b1], 1);
            atomicAdd(&hg[b2], 1);
            atomicAdd(&hg[b3], 1);
        }
    }

    // same-wave DS ordering: atomics above complete before these reads
    if (lane < NBINS) {
        int sum = 0;
        #pragma unroll
        for (int g = 0; g < 8; ++g)
            sum += hw[g * GSTRIDE + lane];
        out[(size_t)row * NBINS + lane] = (float)sum;
    }
}

extern "C" void kernel_launch(void* const* d_in, const int* in_sizes, int n_in,
                              void* d_out, int out_size, void* d_ws, size_t ws_size,
                              hipStream_t stream) {
    const float* simmat = (const float*)d_in[0];
    // d_in[1] = dlens (unused by the reference)
    const int*   dtoks  = (const int*)d_in[2];
    const int*   qtoks  = (const int*)d_in[3];
    float*       out    = (float*)d_out;

    const int nrows = BDIM * CDIM * QDIM;            // 16384
    CountHistogram_kernel<<<nrows / 4, 256, 0, stream>>>(simmat, dtoks, qtoks, out);
}